// Round 1
// baseline (1081.480 us; speedup 1.0000x reference)
//
#include <hip/hip_runtime.h>
#include <hip/hip_bf16.h>

// Problem: B=4, S=1024, D=1024, H=16, DK=64
// d_in: x[4,1024,1024], WQ[16,1024,64], bQ[16,64], WK, bK, WV, bV, WO[1024,1024], bO[1024]
// d_out: output[4,1024,1024] (4,194,304 f32) then weights[4,16,1024,1024] (67,108,864 f32)
// d_ws: Q,K,V [B,H,S,DK] f32 (16 MB each) + concat [4096,1024] f32 (16 MB) = 64 MB

#define S_LEN 1024
#define DMODEL 1024
#define NHEAD 16
#define DK 64
#define M_ROWS 4096  // B*S

// ---------------- Kernel 1: fused QKV projection GEMM ----------------
// C[m, n] for n in [0, 3072): n -> (qkv = n>>10, h = (n&1023)>>6, k = n&63)
// A = x [4096, 1024] row-major; B[d][n] = W{qkv}[h*65536 + d*64 + k]
// 64x64 tiles, 256 threads, 4x4 micro-tile per thread.
__global__ __launch_bounds__(256) void qkv_gemm(
    const float* __restrict__ x,
    const float* __restrict__ WQ, const float* __restrict__ WK, const float* __restrict__ WV,
    const float* __restrict__ bQ, const float* __restrict__ bK, const float* __restrict__ bV,
    float* __restrict__ Q, float* __restrict__ Ko, float* __restrict__ Vo)
{
    __shared__ float As[16][65];
    __shared__ float Bs[16][64];
    const int tid = threadIdx.x;
    const int tx = tid & 15, ty = tid >> 4;
    const int n0 = blockIdx.x * 64;      // 0..3071 (one (qkv,h) per tile)
    const int m0 = blockIdx.y * 64;
    const int qkv = n0 >> 10;
    const int h = (n0 & 1023) >> 6;
    const float* __restrict__ W    = (qkv == 0) ? WQ : (qkv == 1) ? WK : WV;
    const float* __restrict__ bias = (qkv == 0) ? bQ : (qkv == 1) ? bK : bV;
    float* __restrict__ out        = (qkv == 0) ? Q  : (qkv == 1) ? Ko : Vo;

    float acc[4][4] = {};
    for (int d0 = 0; d0 < DMODEL; d0 += 16) {
        #pragma unroll
        for (int i = 0; i < 4; ++i) {                 // A tile: 64 rows x 16 d
            int e = i * 256 + tid;
            int ml = e >> 4, dd = e & 15;
            As[dd][ml] = x[(m0 + ml) * DMODEL + d0 + dd];
        }
        #pragma unroll
        for (int i = 0; i < 4; ++i) {                 // B tile: 16 d x 64 n
            int e = i * 256 + tid;
            int dd = e >> 6, nl = e & 63;
            Bs[dd][nl] = W[h * (DMODEL * DK) + (d0 + dd) * DK + nl];
        }
        __syncthreads();
        #pragma unroll
        for (int dd = 0; dd < 16; ++dd) {
            float a[4], bb[4];
            #pragma unroll
            for (int i = 0; i < 4; ++i) a[i] = As[dd][ty * 4 + i];
            #pragma unroll
            for (int j = 0; j < 4; ++j) bb[j] = Bs[dd][tx * 4 + j];
            #pragma unroll
            for (int i = 0; i < 4; ++i)
                #pragma unroll
                for (int j = 0; j < 4; ++j)
                    acc[i][j] += a[i] * bb[j];
        }
        __syncthreads();
    }
    #pragma unroll
    for (int i = 0; i < 4; ++i) {
        int m = m0 + ty * 4 + i;
        int b = m >> 10, s = m & 1023;
        #pragma unroll
        for (int j = 0; j < 4; ++j) {
            int k = tx * 4 + j;
            out[((b * NHEAD + h) * S_LEN + s) * DK + k] = acc[i][j] + bias[h * DK + k];
        }
    }
}

// ---------------- Kernel 2: fused scores + softmax + PV ----------------
// grid (S/16, B*H). Per block: 16 query rows of one (b,h).
__global__ __launch_bounds__(256) void attn_fused(
    const float* __restrict__ Q, const float* __restrict__ K, const float* __restrict__ V,
    float* __restrict__ weights, float* __restrict__ concat)
{
    __shared__ float Qs[16][64];
    __shared__ float Sc[16][1032];   // 1024 + 8 pad (bank spread across row groups)
    const int tid = threadIdx.x;
    const int bh = blockIdx.y;                // 0..63
    const int b = bh >> 4, h = bh & 15;
    const int r0 = blockIdx.x * 16;
    const float* __restrict__ Qb = Q + (size_t)bh * (S_LEN * DK);
    const float* __restrict__ Kb = K + (size_t)bh * (S_LEN * DK);
    const float* __restrict__ Vb = V + (size_t)bh * (S_LEN * DK);

    // stage Q tile [16][64]
    {
        int r = tid >> 4, c4 = (tid & 15) * 4;
        *(float4*)&Qs[r][c4] = *(const float4*)&Qb[(r0 + r) * DK + c4];
    }
    __syncthreads();

    // ---- scores: S[r][c] = dot(Q[r], K[c]) * 0.125 ; thread t owns cols c_j = j*256 + t
    float acc[16][4];
    #pragma unroll
    for (int r = 0; r < 16; ++r)
        #pragma unroll
        for (int j = 0; j < 4; ++j) acc[r][j] = 0.0f;

    #pragma unroll
    for (int dq = 0; dq < DK; dq += 4) {
        float4 kq[4];
        #pragma unroll
        for (int j = 0; j < 4; ++j)
            kq[j] = *(const float4*)&Kb[(j * 256 + tid) * DK + dq];
        #pragma unroll
        for (int r = 0; r < 16; ++r) {
            float4 qv = *(const float4*)&Qs[r][dq];
            #pragma unroll
            for (int j = 0; j < 4; ++j)
                acc[r][j] += qv.x * kq[j].x + qv.y * kq[j].y + qv.z * kq[j].z + qv.w * kq[j].w;
        }
    }
    #pragma unroll
    for (int r = 0; r < 16; ++r)
        #pragma unroll
        for (int j = 0; j < 4; ++j)
            Sc[r][j * 256 + tid] = acc[r][j] * 0.125f;
    __syncthreads();

    // ---- softmax: 16 lanes per row (rows = tid>>4)
    {
        const int g = tid >> 4;       // row
        const int l16 = tid & 15;
        float mx = -1e30f;
        #pragma unroll
        for (int i = 0; i < 64; ++i) mx = fmaxf(mx, Sc[g][l16 + i * 16]);
        #pragma unroll
        for (int off = 1; off < 16; off <<= 1) mx = fmaxf(mx, __shfl_xor(mx, off, 64));
        float sum = 0.0f;
        #pragma unroll
        for (int i = 0; i < 64; ++i) {
            float e = __expf(Sc[g][l16 + i * 16] - mx);
            Sc[g][l16 + i * 16] = e;
            sum += e;
        }
        #pragma unroll
        for (int off = 1; off < 16; off <<= 1) sum += __shfl_xor(sum, off, 64);
        float rinv = 1.0f / sum;
        float* __restrict__ wrow =
            weights + ((size_t)bh * S_LEN + (r0 + g)) * S_LEN;
        #pragma unroll
        for (int i = 0; i < 64; ++i) {
            int c = l16 + i * 16;
            float w = Sc[g][c] * rinv;
            Sc[g][c] = w;
            wrow[c] = w;
        }
    }
    __syncthreads();

    // ---- PV: heads[r][k] = sum_c w[r][c] * V[c][k]
    {
        const int k = tid & 63;
        const int rg = tid >> 6;      // 0..3 -> rows rg*4 .. rg*4+3
        float acc2[4] = {0.0f, 0.0f, 0.0f, 0.0f};
        for (int c = 0; c < S_LEN; c += 4) {
            #pragma unroll
            for (int cc = 0; cc < 4; ++cc) {
                float v = Vb[(c + cc) * DK + k];
                #pragma unroll
                for (int rr = 0; rr < 4; ++rr)
                    acc2[rr] += Sc[rg * 4 + rr][c + cc] * v;
            }
        }
        #pragma unroll
        for (int rr = 0; rr < 4; ++rr) {
            int s = r0 + rg * 4 + rr;
            concat[((size_t)b * S_LEN + s) * DMODEL + h * DK + k] = acc2[rr];
        }
    }
}

// ---------------- Kernel 3: output projection GEMM ----------------
__global__ __launch_bounds__(256) void out_gemm(
    const float* __restrict__ Cc, const float* __restrict__ WO,
    const float* __restrict__ bO, float* __restrict__ out)
{
    __shared__ float As[16][65];
    __shared__ float Bs[16][64];
    const int tid = threadIdx.x;
    const int tx = tid & 15, ty = tid >> 4;
    const int n0 = blockIdx.x * 64;
    const int m0 = blockIdx.y * 64;

    float acc[4][4] = {};
    for (int d0 = 0; d0 < DMODEL; d0 += 16) {
        #pragma unroll
        for (int i = 0; i < 4; ++i) {
            int e = i * 256 + tid;
            int ml = e >> 4, dd = e & 15;
            As[dd][ml] = Cc[(m0 + ml) * DMODEL + d0 + dd];
        }
        #pragma unroll
        for (int i = 0; i < 4; ++i) {
            int e = i * 256 + tid;
            int dd = e >> 6, nl = e & 63;
            Bs[dd][nl] = WO[(d0 + dd) * DMODEL + n0 + nl];
        }
        __syncthreads();
        #pragma unroll
        for (int dd = 0; dd < 16; ++dd) {
            float a[4], bb[4];
            #pragma unroll
            for (int i = 0; i < 4; ++i) a[i] = As[dd][ty * 4 + i];
            #pragma unroll
            for (int j = 0; j < 4; ++j) bb[j] = Bs[dd][tx * 4 + j];
            #pragma unroll
            for (int i = 0; i < 4; ++i)
                #pragma unroll
                for (int j = 0; j < 4; ++j)
                    acc[i][j] += a[i] * bb[j];
        }
        __syncthreads();
    }
    #pragma unroll
    for (int i = 0; i < 4; ++i) {
        int m = m0 + ty * 4 + i;
        #pragma unroll
        for (int j = 0; j < 4; ++j) {
            int n = n0 + tx * 4 + j;
            out[(size_t)m * DMODEL + n] = acc[i][j] + bO[n];
        }
    }
}

extern "C" void kernel_launch(void* const* d_in, const int* in_sizes, int n_in,
                              void* d_out, int out_size, void* d_ws, size_t ws_size,
                              hipStream_t stream) {
    const float* x  = (const float*)d_in[0];
    const float* WQ = (const float*)d_in[1];
    const float* bQ = (const float*)d_in[2];
    const float* WK = (const float*)d_in[3];
    const float* bK = (const float*)d_in[4];
    const float* WV = (const float*)d_in[5];
    const float* bV = (const float*)d_in[6];
    const float* WO = (const float*)d_in[7];
    const float* bO = (const float*)d_in[8];

    float* out     = (float*)d_out;                       // [4096, 1024]
    float* weights = out + (size_t)4 * 1024 * 1024;       // [64, 1024, 1024]

    float* Q  = (float*)d_ws;                             // [B,H,S,DK] each 4,194,304 f32
    float* K  = Q + (size_t)4 * 1024 * 1024;
    float* V  = K + (size_t)4 * 1024 * 1024;
    float* Cc = V + (size_t)4 * 1024 * 1024;              // concat [4096, 1024]

    qkv_gemm<<<dim3(48, 64), 256, 0, stream>>>(x, WQ, WK, WV, bQ, bK, bV, Q, K, V);
    attn_fused<<<dim3(64, 64), 256, 0, stream>>>(Q, K, V, weights, Cc);
    out_gemm<<<dim3(16, 64), 256, 0, stream>>>(Cc, WO, bO, out);
}

// Round 2
// 260.132 us; speedup vs baseline: 4.1574x; 4.1574x over previous
//
#include <hip/hip_runtime.h>
#include <hip/hip_bf16.h>

// B=4, S=1024, D=1024, H=16, DK=64
// d_out: output[4096][1024] f32, then weights[64][1024][1024] f32
// ws: xb 8MB | Wt 6MB | WOt 2MB | Qb 8MB | Kb 8MB | Vt 8MB | concat 8MB = 48MB

typedef unsigned short u16;
typedef __attribute__((ext_vector_type(8))) short bf16x8;
typedef __attribute__((ext_vector_type(4))) short s16x4;
typedef __attribute__((ext_vector_type(4))) float f32x4;

__device__ __forceinline__ u16 f2bf(float f) {
    union { float f; unsigned u; } v; v.f = f;
    unsigned r = (v.u + 0x7FFFu + ((v.u >> 16) & 1u)) >> 16;
    return (u16)r;
}

#define MFMA(a, b, c) __builtin_amdgcn_mfma_f32_16x16x32_bf16(a, b, c, 0, 0, 0)

// ---------------- convert x (and concat path uses bf16 written by attn) ----------------
__global__ __launch_bounds__(256) void f32_to_bf16_vec(const float* __restrict__ in,
                                                       u16* __restrict__ out, int n8) {
    int i = blockIdx.x * 256 + threadIdx.x;
    if (i >= n8) return;
    const f32x4* p = (const f32x4*)(in + (size_t)i * 8);
    f32x4 a = p[0], b = p[1];
    bf16x8 o;
    #pragma unroll
    for (int j = 0; j < 4; ++j) { o[j] = (short)f2bf(a[j]); o[4 + j] = (short)f2bf(b[j]); }
    *(bf16x8*)(out + (size_t)i * 8) = o;
}

// ---------------- transpose per-head weights: W[h][1024][64] -> Wt[n][1024] ----------------
__global__ __launch_bounds__(256) void transpose_w_heads(
    const float* __restrict__ WQ, const float* __restrict__ WK, const float* __restrict__ WV,
    u16* __restrict__ Wt) {
    __shared__ float L[64][68];
    const int z = blockIdx.y;               // 0..47 = qkv*16 + h
    const int qkv = z >> 4, h = z & 15;
    const float* __restrict__ W = ((qkv == 0) ? WQ : (qkv == 1) ? WK : WV) + (size_t)h * 65536;
    const int d0 = blockIdx.x * 64;
    const int t = threadIdx.x;
    #pragma unroll
    for (int j = 0; j < 4; ++j) {
        int dd = j * 16 + (t >> 4);
        int k4 = (t & 15) * 4;
        *(f32x4*)&L[dd][k4] = *(const f32x4*)(W + (size_t)(d0 + dd) * 64 + k4);
    }
    __syncthreads();
    const int k = t >> 2, part = t & 3;
    u16* dst = Wt + (size_t)(z * 64 + k) * 1024 + d0 + part * 16;
    bf16x8 o0, o1;
    #pragma unroll
    for (int j = 0; j < 8; ++j) {
        o0[j] = (short)f2bf(L[part * 16 + j][k]);
        o1[j] = (short)f2bf(L[part * 16 + 8 + j][k]);
    }
    *(bf16x8*)dst = o0;
    *(bf16x8*)(dst + 8) = o1;
}

// ---------------- transpose WO [1024][1024] -> WOt[n][d] bf16 ----------------
__global__ __launch_bounds__(256) void transpose_wo(const float* __restrict__ WO,
                                                    u16* __restrict__ WOt) {
    __shared__ float L[64][68];
    const int r0 = blockIdx.x * 64;   // d
    const int c0 = blockIdx.y * 64;   // n
    const int t = threadIdx.x;
    #pragma unroll
    for (int j = 0; j < 4; ++j) {
        int dd = j * 16 + (t >> 4);
        int k4 = (t & 15) * 4;
        *(f32x4*)&L[dd][k4] = *(const f32x4*)(WO + (size_t)(r0 + dd) * 1024 + c0 + k4);
    }
    __syncthreads();
    const int n = t >> 2, part = t & 3;
    u16* dst = WOt + (size_t)(c0 + n) * 1024 + r0 + part * 16;
    bf16x8 o0, o1;
    #pragma unroll
    for (int j = 0; j < 8; ++j) {
        o0[j] = (short)f2bf(L[part * 16 + j][n]);
        o1[j] = (short)f2bf(L[part * 16 + 8 + j][n]);
    }
    *(bf16x8*)dst = o0;
    *(bf16x8*)(dst + 8) = o1;
}

// ---------------- QKV GEMM: [4096x1024] x [1024x3072] bf16 MFMA ----------------
// Q,K out: [bh][s][64] bf16 ; V out transposed: [bh][64][s] bf16
__global__ __launch_bounds__(256) void qkv_gemm_mfma(
    const u16* __restrict__ xb, const u16* __restrict__ Wt,
    const float* __restrict__ bQ, const float* __restrict__ bK, const float* __restrict__ bV,
    u16* __restrict__ Qo, u16* __restrict__ Ko, u16* __restrict__ Vo) {
    __shared__ u16 smem[16640];            // 32KB staging / 33.3KB Ct (union)
    u16* As = smem;                        // [128][64] swizzled
    u16* Bs = smem + 8192;
    const int tid = threadIdx.x;
    const int wv = tid >> 6, lane = tid & 63, g = lane >> 4, l15 = lane & 15;
    const int wr = wv >> 1, wc = wv & 1;
    const int id = blockIdx.x;             // 768 = 24n x 32m
    const int swz = (id & 7) * 96 + (id >> 3);
    const int nt = swz % 24, mt = swz / 24;
    const int m0 = mt * 128, n0 = nt * 128;

    f32x4 acc[4][4];
    #pragma unroll
    for (int i = 0; i < 4; ++i)
        #pragma unroll
        for (int j = 0; j < 4; ++j) acc[i][j] = (f32x4){0.f, 0.f, 0.f, 0.f};

    for (int kt = 0; kt < 16; ++kt) {
        const int k0 = kt * 64;
        bf16x8 ra[4], rb[4];
        #pragma unroll
        for (int j = 0; j < 4; ++j) {
            int v = j * 256 + tid;
            int row = v >> 3, slot = v & 7;
            ra[j] = *(const bf16x8*)(xb + (size_t)(m0 + row) * 1024 + k0 + slot * 8);
            rb[j] = *(const bf16x8*)(Wt + (size_t)(n0 + row) * 1024 + k0 + slot * 8);
        }
        __syncthreads();
        #pragma unroll
        for (int j = 0; j < 4; ++j) {
            int v = j * 256 + tid;
            int row = v >> 3, slot = v & 7;
            int uo = row * 64 + ((slot ^ (row & 7)) * 8);
            *(bf16x8*)(As + uo) = ra[j];
            *(bf16x8*)(Bs + uo) = rb[j];
        }
        __syncthreads();
        bf16x8 af[4][2], bfr[4][2];
        #pragma unroll
        for (int am = 0; am < 4; ++am) {
            int row = wr * 64 + am * 16 + l15;
            #pragma unroll
            for (int kk = 0; kk < 2; ++kk)
                af[am][kk] = *(const bf16x8*)(As + row * 64 + (((kk * 4 + g) ^ (l15 & 7)) * 8));
        }
        #pragma unroll
        for (int bn = 0; bn < 4; ++bn) {
            int row = wc * 64 + bn * 16 + l15;
            #pragma unroll
            for (int kk = 0; kk < 2; ++kk)
                bfr[bn][kk] = *(const bf16x8*)(Bs + row * 64 + (((kk * 4 + g) ^ (l15 & 7)) * 8));
        }
        #pragma unroll
        for (int am = 0; am < 4; ++am)
            #pragma unroll
            for (int bn = 0; bn < 4; ++bn) {
                acc[am][bn] = MFMA(af[am][0], bfr[bn][0], acc[am][bn]);
                acc[am][bn] = MFMA(af[am][1], bfr[bn][1], acc[am][bn]);
            }
        if (kt < 15) __syncthreads();
    }

    // epilogue: wave covers one head (64 cols)
    const int nbase = n0 + wc * 64;
    const int qkv = nbase >> 10;
    const int h = (nbase >> 6) & 15;
    const float* __restrict__ bias = (qkv == 0) ? bQ : (qkv == 1) ? bK : bV;
    const int b = m0 >> 10, srow0 = m0 & 1023;

    if (qkv < 2) {
        u16* out = ((qkv == 0) ? Qo : Ko) + (size_t)(b * 16 + h) * 65536;
        #pragma unroll
        for (int am = 0; am < 4; ++am)
            #pragma unroll
            for (int bn = 0; bn < 4; ++bn) {
                int k = bn * 16 + l15;
                float bv = bias[h * 64 + k];
                #pragma unroll
                for (int i = 0; i < 4; ++i) {
                    int s = srow0 + wr * 64 + am * 16 + 4 * g + i;
                    out[(size_t)s * 64 + k] = f2bf(acc[am][bn][i] + bv);
                }
            }
    } else {
        __syncthreads();                        // staging LDS dead; reuse as Ct
        u16 (*Ct)[130] = (u16(*)[130])smem;
        #pragma unroll
        for (int am = 0; am < 4; ++am)
            #pragma unroll
            for (int bn = 0; bn < 4; ++bn) {
                int k = bn * 16 + l15;
                float bv = bias[h * 64 + k];
                int nn = wc * 64 + bn * 16 + l15;
                #pragma unroll
                for (int i = 0; i < 4; ++i) {
                    int mr = wr * 64 + am * 16 + 4 * g + i;
                    Ct[mr][nn] = f2bf(acc[am][bn][i] + bv);
                }
            }
        __syncthreads();
        #pragma unroll
        for (int c8 = 0; c8 < 8; ++c8) {
            int nn = c8 * 16 + (tid >> 4);
            int hv = ((n0 + nn) >> 6) & 15;
            int k = nn & 63;
            int s0 = (tid & 15) * 8;
            bf16x8 pk;
            #pragma unroll
            for (int j = 0; j < 8; ++j) pk[j] = (short)Ct[s0 + j][nn];
            *(bf16x8*)(Vo + ((size_t)(b * 16 + hv) * 64 + k) * 1024 + srow0 + s0) = pk;
        }
    }
}

// ---------------- fused attention: MFMA QK^T + softmax + weights + MFMA PV ----------------
__global__ __launch_bounds__(256) void attn_mfma(
    const u16* __restrict__ Qb, const u16* __restrict__ Kb, const u16* __restrict__ Vt,
    float* __restrict__ weights, u16* __restrict__ concat) {
    __shared__ float Sc[16][1028];
    const int id = blockIdx.x;                 // 4096 = 64bh x 64qt
    const int swz = (id & 7) * 512 + (id >> 3);
    const int bh = swz >> 6, qt = swz & 63;
    const int b = bh >> 4, h = bh & 15;
    const int q0 = qt * 16;
    const int tid = threadIdx.x, w = tid >> 6, lane = tid & 63, g = lane >> 4, l15 = lane & 15;
    const u16* __restrict__ Qp = Qb + ((size_t)bh * 1024 + q0) * 64;
    const u16* __restrict__ Kp = Kb + (size_t)bh * 65536;
    const u16* __restrict__ Vp = Vt + (size_t)bh * 65536;

    // ---- QK^T: wave w owns cols [w*256, w*256+256)
    bf16x8 qf0 = *(const bf16x8*)(Qp + l15 * 64 + g * 8);
    bf16x8 qf1 = *(const bf16x8*)(Qp + l15 * 64 + 32 + g * 8);
    const int c0 = w * 256;
    f32x4 acc[16];
    #pragma unroll
    for (int cf = 0; cf < 16; ++cf) acc[cf] = (f32x4){0.f, 0.f, 0.f, 0.f};
    #pragma unroll
    for (int cf = 0; cf < 16; ++cf) {
        const u16* kp = Kp + (size_t)(c0 + cf * 16 + l15) * 64 + g * 8;
        bf16x8 kv0 = *(const bf16x8*)kp;
        bf16x8 kv1 = *(const bf16x8*)(kp + 32);
        acc[cf] = MFMA(qf0, kv0, acc[cf]);
        acc[cf] = MFMA(qf1, kv1, acc[cf]);
    }
    #pragma unroll
    for (int cf = 0; cf < 16; ++cf)
        #pragma unroll
        for (int i = 0; i < 4; ++i)
            Sc[4 * g + i][c0 + cf * 16 + l15] = acc[cf][i] * 0.125f;
    __syncthreads();

    // ---- softmax (row r = tid>>4, 16 lanes per row)
    {
        const int r = tid >> 4, l16 = tid & 15;
        float mx = -1e30f;
        #pragma unroll
        for (int i = 0; i < 64; ++i) mx = fmaxf(mx, Sc[r][l16 + i * 16]);
        #pragma unroll
        for (int off = 1; off < 16; off <<= 1) mx = fmaxf(mx, __shfl_xor(mx, off, 64));
        float sum = 0.f;
        #pragma unroll
        for (int i = 0; i < 64; ++i) {
            float e = __expf(Sc[r][l16 + i * 16] - mx);
            Sc[r][l16 + i * 16] = e;
            sum += e;
        }
        #pragma unroll
        for (int off = 1; off < 16; off <<= 1) sum += __shfl_xor(sum, off, 64);
        float rinv = 1.0f / sum;
        #pragma unroll
        for (int i = 0; i < 64; ++i) Sc[r][l16 + i * 16] *= rinv;
    }
    __syncthreads();

    // ---- weights write (coalesced float4), wave w rows w*4..w*4+3
    #pragma unroll
    for (int rr = 0; rr < 4; ++rr) {
        int rw = w * 4 + rr;
        float* dst = weights + ((size_t)bh * 1024 + q0 + rw) * 1024;
        #pragma unroll
        for (int j = 0; j < 4; ++j) {
            int c = j * 256 + lane * 4;
            *(f32x4*)(dst + c) = *(const f32x4*)&Sc[rw][c];
        }
    }

    // ---- PV: wave w owns s-slice [w*256, +256); A = P (from Sc, ->bf16), B = Vt
    f32x4 oacc[4];
    #pragma unroll
    for (int vf = 0; vf < 4; ++vf) oacc[vf] = (f32x4){0.f, 0.f, 0.f, 0.f};
    #pragma unroll
    for (int kst = 0; kst < 8; ++kst) {
        int sloc = w * 256 + kst * 32 + g * 8;
        f32x4 p0 = *(const f32x4*)&Sc[l15][sloc];
        f32x4 p1 = *(const f32x4*)&Sc[l15][sloc + 4];
        bf16x8 pa;
        #pragma unroll
        for (int i = 0; i < 4; ++i) {
            pa[i] = (short)f2bf(p0[i]);
            pa[4 + i] = (short)f2bf(p1[i]);
        }
        #pragma unroll
        for (int vf = 0; vf < 4; ++vf) {
            bf16x8 vb = *(const bf16x8*)(Vp + (size_t)(vf * 16 + l15) * 1024 + sloc);
            oacc[vf] = MFMA(pa, vb, oacc[vf]);
        }
    }
    __syncthreads();
    float (*Osc)[16][68] = (float(*)[16][68])&Sc[0][0];
    #pragma unroll
    for (int vf = 0; vf < 4; ++vf)
        #pragma unroll
        for (int i = 0; i < 4; ++i)
            Osc[w][4 * g + i][vf * 16 + l15] = oacc[vf][i];
    __syncthreads();
    {
        const int rr = tid >> 4, v0 = (tid & 15) * 4;
        f32x4 o = *(const f32x4*)&Osc[0][rr][v0];
        #pragma unroll
        for (int ww = 1; ww < 4; ++ww) o += *(const f32x4*)&Osc[ww][rr][v0];
        s16x4 ob;
        #pragma unroll
        for (int i = 0; i < 4; ++i) ob[i] = (short)f2bf(o[i]);
        *(s16x4*)(concat + ((size_t)(b * 1024 + q0 + rr)) * 1024 + h * 64 + v0) = ob;
    }
}

// ---------------- out GEMM: concat(bf16) x WOt -> f32 out + bO ----------------
__global__ __launch_bounds__(256) void out_gemm_mfma(
    const u16* __restrict__ Cc, const u16* __restrict__ WOt,
    const float* __restrict__ bO, float* __restrict__ out) {
    __shared__ u16 smem[16384];
    u16* As = smem;
    u16* Bs = smem + 8192;
    const int tid = threadIdx.x;
    const int wv = tid >> 6, lane = tid & 63, g = lane >> 4, l15 = lane & 15;
    const int wr = wv >> 1, wc = wv & 1;
    const int id = blockIdx.x;              // 256 = 8n x 32m
    const int swz = (id & 7) * 32 + (id >> 3);
    const int nt = swz & 7, mt = swz >> 3;
    const int m0 = mt * 128, n0 = nt * 128;

    f32x4 acc[4][4];
    #pragma unroll
    for (int i = 0; i < 4; ++i)
        #pragma unroll
        for (int j = 0; j < 4; ++j) acc[i][j] = (f32x4){0.f, 0.f, 0.f, 0.f};

    for (int kt = 0; kt < 16; ++kt) {
        const int k0 = kt * 64;
        bf16x8 ra[4], rb[4];
        #pragma unroll
        for (int j = 0; j < 4; ++j) {
            int v = j * 256 + tid;
            int row = v >> 3, slot = v & 7;
            ra[j] = *(const bf16x8*)(Cc + (size_t)(m0 + row) * 1024 + k0 + slot * 8);
            rb[j] = *(const bf16x8*)(WOt + (size_t)(n0 + row) * 1024 + k0 + slot * 8);
        }
        __syncthreads();
        #pragma unroll
        for (int j = 0; j < 4; ++j) {
            int v = j * 256 + tid;
            int row = v >> 3, slot = v & 7;
            int uo = row * 64 + ((slot ^ (row & 7)) * 8);
            *(bf16x8*)(As + uo) = ra[j];
            *(bf16x8*)(Bs + uo) = rb[j];
        }
        __syncthreads();
        bf16x8 af[4][2], bfr[4][2];
        #pragma unroll
        for (int am = 0; am < 4; ++am) {
            int row = wr * 64 + am * 16 + l15;
            #pragma unroll
            for (int kk = 0; kk < 2; ++kk)
                af[am][kk] = *(const bf16x8*)(As + row * 64 + (((kk * 4 + g) ^ (l15 & 7)) * 8));
        }
        #pragma unroll
        for (int bn = 0; bn < 4; ++bn) {
            int row = wc * 64 + bn * 16 + l15;
            #pragma unroll
            for (int kk = 0; kk < 2; ++kk)
                bfr[bn][kk] = *(const bf16x8*)(Bs + row * 64 + (((kk * 4 + g) ^ (l15 & 7)) * 8));
        }
        #pragma unroll
        for (int am = 0; am < 4; ++am)
            #pragma unroll
            for (int bn = 0; bn < 4; ++bn) {
                acc[am][bn] = MFMA(af[am][0], bfr[bn][0], acc[am][bn]);
                acc[am][bn] = MFMA(af[am][1], bfr[bn][1], acc[am][bn]);
            }
        if (kt < 15) __syncthreads();
    }
    #pragma unroll
    for (int am = 0; am < 4; ++am)
        #pragma unroll
        for (int bn = 0; bn < 4; ++bn) {
            int n = n0 + wc * 64 + bn * 16 + l15;
            float bv = bO[n];
            #pragma unroll
            for (int i = 0; i < 4; ++i) {
                int m = m0 + wr * 64 + am * 16 + 4 * g + i;
                out[(size_t)m * 1024 + n] = acc[am][bn][i] + bv;
            }
        }
}

extern "C" void kernel_launch(void* const* d_in, const int* in_sizes, int n_in,
                              void* d_out, int out_size, void* d_ws, size_t ws_size,
                              hipStream_t stream) {
    const float* x  = (const float*)d_in[0];
    const float* WQ = (const float*)d_in[1];
    const float* bQ = (const float*)d_in[2];
    const float* WK = (const float*)d_in[3];
    const float* bK = (const float*)d_in[4];
    const float* WV = (const float*)d_in[5];
    const float* bV = (const float*)d_in[6];
    const float* WO = (const float*)d_in[7];
    const float* bO = (const float*)d_in[8];

    float* out     = (float*)d_out;
    float* weights = out + (size_t)4 * 1024 * 1024;

    char* ws = (char*)d_ws;
    u16* xb  = (u16*)(ws);
    u16* Wt  = (u16*)(ws + ((size_t)8  << 20));
    u16* WOt = (u16*)(ws + ((size_t)14 << 20));
    u16* Qb  = (u16*)(ws + ((size_t)16 << 20));
    u16* Kb  = (u16*)(ws + ((size_t)24 << 20));
    u16* Vtb = (u16*)(ws + ((size_t)32 << 20));
    u16* Cc  = (u16*)(ws + ((size_t)40 << 20));

    f32_to_bf16_vec<<<2048, 256, 0, stream>>>(x, xb, 524288);
    transpose_w_heads<<<dim3(16, 48), 256, 0, stream>>>(WQ, WK, WV, Wt);
    transpose_wo<<<dim3(16, 16), 256, 0, stream>>>(WO, WOt);
    qkv_gemm_mfma<<<768, 256, 0, stream>>>(xb, Wt, bQ, bK, bV, Qb, Kb, Vtb);
    attn_mfma<<<4096, 256, 0, stream>>>(Qb, Kb, Vtb, weights, Cc);
    out_gemm_mfma<<<256, 256, 0, stream>>>(Cc, WOt, bO, out);
}